// Round 1
// baseline (252.292 us; speedup 1.0000x reference)
//
#include <hip/hip_runtime.h>
#include <math.h>

namespace {

constexpr int kB   = 64;
constexpr int kCin = 8;
constexpr int kR   = 800;
constexpr int kNC  = 128;
constexpr int kO   = 16;
constexpr int TPB  = 256;
constexpr int RPT  = 4;    // r's per thread: r = tid + 256*j  (j=3 valid only for tid<32)
constexpr int NITER = 3;

// Block-wide max over one float. Uses its own 4-float LDS scratch.
__device__ __forceinline__ float block_max(float v, volatile float* mred, int tid) {
  #pragma unroll
  for (int off = 32; off >= 1; off >>= 1)
    v = fmaxf(v, __shfl_xor(v, off, 64));
  if ((tid & 63) == 0) mred[tid >> 6] = v;
  __syncthreads();
  v = fmaxf(fmaxf(mred[0], mred[1]), fmaxf(mred[2], mred[3]));
  __syncthreads();
  return v;
}

__global__ __launch_bounds__(TPB, 2) void caps_route(
    const float* __restrict__ x, const float* __restrict__ W,
    float* __restrict__ out) {
  // stride-17 padding: lanes index rows -> banks spread, 2-way aliasing (free)
  __shared__ float ldsP0[256 * 17];   // 17.0 KB  prior staging tile, b0
  __shared__ float ldsP1[256 * 17];   // 17.0 KB  prior staging tile, b1
  __shared__ float red[64 * 17];      //  4.3 KB  s[16]+Z reduction rows
  __shared__ float red2[4 * 17];
  __shared__ float sh_s[17];          // broadcast: s[0..15], Z
  __shared__ float mred[4];

  const int tid = threadIdx.x;

  // XCD swizzle: all 32 blocks sharing one c land on (heuristically) one XCD,
  // so W[c] (409.6 KB) stays resident in that XCD's 4 MB L2.
  const int j   = blockIdx.x;
  const int xcd = j & 7;
  const int k   = j >> 3;               // 0..511 per xcd
  const int c   = ((k >> 5) << 3) + xcd; // 16 c's per xcd
  const int bg  = k & 31;
  const int b0  = bg * 2, b1 = b0 + 1;

  float P0[RPT][kO];   // priors for b0, this thread's 4 r-rows (registers)
  float P1[RPT][kO];   // priors for b1

  const float* Wc  = W + (size_t)c * kR * kCin * kO;
  const float* x0p = x + (size_t)b0 * kCin * kR;
  const float* x1p = x + (size_t)b1 * kCin * kR;

  // ---------------- Phase 1: priors ----------------
  // Unit (r, oc): 4 lanes with consecutive oc read one full 64B line of W
  // (perfect coalescing). Results staged in LDS, then picked up into the
  // owning thread's registers (thread t owns r = T*256 + t).
  #pragma unroll
  for (int T = 0; T < RPT; ++T) {
    const int rbase = T * 256;
    #pragma unroll
    for (int s = 0; s < 4; ++s) {
      const int rl = s * 64 + (tid >> 2);
      const int oc = tid & 3;
      const int r  = rbase + rl;
      if (r < kR) {
        float xv0[kCin], xv1[kCin];
        #pragma unroll
        for (int i = 0; i < kCin; ++i) {
          xv0[i] = x0p[i * kR + r];
          xv1[i] = x1p[i * kR + r];
        }
        const float4* Wr = reinterpret_cast<const float4*>(Wc + (size_t)r * kCin * kO);
        float4 a0 = make_float4(0.f, 0.f, 0.f, 0.f);
        float4 a1 = make_float4(0.f, 0.f, 0.f, 0.f);
        #pragma unroll
        for (int i = 0; i < kCin; ++i) {
          const float4 w = Wr[i * 4 + oc];
          a0.x += xv0[i] * w.x; a0.y += xv0[i] * w.y;
          a0.z += xv0[i] * w.z; a0.w += xv0[i] * w.w;
          a1.x += xv1[i] * w.x; a1.y += xv1[i] * w.y;
          a1.z += xv1[i] * w.z; a1.w += xv1[i] * w.w;
        }
        const int base = rl * 17 + oc * 4;
        ldsP0[base + 0] = a0.x; ldsP0[base + 1] = a0.y;
        ldsP0[base + 2] = a0.z; ldsP0[base + 3] = a0.w;
        ldsP1[base + 0] = a1.x; ldsP1[base + 1] = a1.y;
        ldsP1[base + 2] = a1.z; ldsP1[base + 3] = a1.w;
      }
    }
    __syncthreads();
    if (rbase + tid < kR) {
      #pragma unroll
      for (int o = 0; o < kO; ++o) {
        P0[T][o] = ldsP0[tid * 17 + o];
        P1[T][o] = ldsP1[tid * 17 + o];
      }
    }
    __syncthreads();
  }

  // ---------------- Phase 2: routing (independent per b) ----------------
  const bool v3 = (tid < kR - 3 * 256);   // tid < 32: owns r = 768+tid

  auto route = [&](float (&P)[RPT][kO], int b) {
    float l[RPT] = {0.f, 0.f, 0.f, 0.f};
    #pragma unroll
    for (int it = 0; it < NITER; ++it) {
      // softmax max over the 800 logits
      float lm = fmaxf(fmaxf(l[0], l[1]), l[2]);
      if (v3) lm = fmaxf(lm, l[3]);
      const float m = block_max(lm, mred, tid);

      // e = exp(l - m); local partials of s[o] = sum_r e*P[r,o] and Z = sum_r e
      float sp[kO];
      #pragma unroll
      for (int o = 0; o < kO; ++o) sp[o] = 0.f;
      float Zp = 0.f;
      #pragma unroll
      for (int jj = 0; jj < RPT; ++jj) {
        if (jj < 3 || v3) {
          const float e = __expf(l[jj] - m);
          Zp += e;
          #pragma unroll
          for (int o = 0; o < kO; ++o) sp[o] += e * P[jj][o];
        }
      }

      // 17-wide block reduction: xor-1/2 shuffles, then 2-stage LDS tree
      #pragma unroll
      for (int o = 0; o < kO; ++o) {
        sp[o] += __shfl_xor(sp[o], 1, 64);
        sp[o] += __shfl_xor(sp[o], 2, 64);
      }
      Zp += __shfl_xor(Zp, 1, 64);
      Zp += __shfl_xor(Zp, 2, 64);
      const int lane = tid & 63;
      if ((lane & 3) == 0) {
        const int row = (tid >> 6) * 16 + (lane >> 2);
        #pragma unroll
        for (int o = 0; o < kO; ++o) red[row * 17 + o] = sp[o];
        red[row * 17 + kO] = Zp;
      }
      __syncthreads();
      if (tid < 68) {
        const int q = tid / 17, col = tid % 17;
        float a = 0.f;
        #pragma unroll
        for (int rr = 0; rr < 16; ++rr) a += red[(q * 16 + rr) * 17 + col];
        red2[q * 17 + col] = a;
      }
      __syncthreads();
      if (tid < 17) {
        sh_s[tid] = red2[tid] + red2[17 + tid] + red2[34 + tid] + red2[51 + tid];
      }
      __syncthreads();

      // squash (computed redundantly by every thread from the broadcast s)
      const float Zinv = 1.f / sh_s[kO];
      float sv[kO];
      float sn = 0.f;
      #pragma unroll
      for (int o = 0; o < kO; ++o) {
        const float t = sh_s[o] * Zinv;
        sv[o] = t;
        sn += t * t;
      }
      const float fac = sqrtf(sn) / (1.f + sn);   // v[o] = sv[o]*fac

      if (it < NITER - 1) {
        // delta[r] = sum_o P[r,o]*v[o] — fully thread-local
        #pragma unroll
        for (int jj = 0; jj < RPT; ++jj) {
          if (jj < 3 || v3) {
            float d = 0.f;
            #pragma unroll
            for (int o = 0; o < kO; ++o) d += P[jj][o] * sv[o];
            l[jj] += d * fac;
          }
        }
      } else {
        if (tid < kO) {
          // out[b, o, c], shape [B, O, NC]
          out[(size_t)b * kO * kNC + tid * kNC + c] = sv[tid] * fac;
        }
      }
    }
  };

  route(P0, b0);
  route(P1, b1);
}

}  // namespace

extern "C" void kernel_launch(void* const* d_in, const int* in_sizes, int n_in,
                              void* d_out, int out_size, void* d_ws, size_t ws_size,
                              hipStream_t stream) {
  const float* x = (const float*)d_in[0];          // [64, 8, 800] fp32
  const float* W = (const float*)d_in[1];          // [128, 800, 8, 16] fp32
  float* out = (float*)d_out;                      // [64, 16, 128] fp32
  (void)in_sizes; (void)n_in; (void)out_size; (void)d_ws; (void)ws_size;
  const int grid = kNC * (kB / 2);                 // 4096 blocks: (c, b-pair)
  caps_route<<<dim3(grid), dim3(TPB), 0, stream>>>(x, W, out);
}